// Round 13
// baseline (140.059 us; speedup 1.0000x reference)
//
#include <hip/hip_runtime.h>

typedef __bf16 bhalf;
typedef bhalf bhalf8 __attribute__((ext_vector_type(8)));
typedef float f32x4 __attribute__((ext_vector_type(4)));
typedef unsigned short u16;
typedef u16 u16x8 __attribute__((ext_vector_type(8)));

__device__ __forceinline__ u16 f2bf(float f) {
  union { float f; unsigned u; } v; v.f = f;
  unsigned r = v.u + 0x7FFFu + ((v.u >> 16) & 1u);
  return (u16)(r >> 16);
}

// XOR swizzles (involutions): swz for 128B/64B-row tiles (key bits 7-9),
// swz2 for 1024B-row tiles (key bits 10-12). Both flip byte bits 4-6.
__device__ __forceinline__ int swz(int L)  { return L ^ (((L >> 7)  & 7) << 4); }
__device__ __forceinline__ int swz2(int L) { return L ^ (((L >> 10) & 7) << 4); }

#define GLL16(gp, lp) __builtin_amdgcn_global_load_lds( \
    (const __attribute__((address_space(1))) unsigned int*)(gp), \
    (__attribute__((address_space(3))) unsigned int*)(lp), 16, 0, 0)

#define SB() __builtin_amdgcn_sched_barrier(0)

// W0: [512][784] f32 -> bf16 [512][832] zero-pad (13 K-tiles of 64); W1: [256][512]; W2 pad 16x256.
#define KP0 832
#define W0E (512 * KP0)
#define W1E (256 * 512)
#define W2E (16 * 256)

__global__ __launch_bounds__(256) void cvt_weights(
    const float* __restrict__ W0, const float* __restrict__ W1,
    const float* __restrict__ W2,
    u16* __restrict__ W0b, u16* __restrict__ W1b, u16* __restrict__ W2b)
{
  int i = blockIdx.x * 256 + threadIdx.x;
  if (i < W0E) {
    int r = i / KP0, k = i - r * KP0;
    W0b[i] = (k < 784) ? f2bf(W0[r * 784 + k]) : (u16)0;
    return;
  }
  i -= W0E;
  if (i < W1E) { W1b[i] = f2bf(W1[i]); return; }
  i -= W1E;
  if (i < W2E) {
    int r = i >> 8, c = i & 255;
    W2b[i] = (r < 10) ? f2bf(W2[r * 256 + c]) : (u16)0;
  }
}

// FUSED all 3 layers. Block = 128 rows. Layer-1: r12's 8-phase 128x512 (x read once),
// m1 tile stays in acc registers. Then per 64-row half: scatter relu(m1)->LDS (swz2),
// layer-2 (K=512, BK=64, W1 gll dbuf), m2->LDS, layer-3 -> out. m1 NEVER touches HBM.
__global__ __launch_bounds__(512) void fused3(
    const float* __restrict__ x, const u16* __restrict__ Wb,
    const u16* __restrict__ W1b, const u16* __restrict__ W2b,
    float* __restrict__ out)
{
  extern __shared__ u16 ldsu[];      // 128 KB dynamic
  char* lds = (char*)ldsu;
  const int t = threadIdx.x, w = t >> 6, lane = t & 63;
  const size_t rbase = (size_t)blockIdx.x * 128;
  const int wr = w >> 2, wc = w & 3, fr = lane & 15, fg = lane >> 4;

  // ================= layer 1 (verbatim r12 structure) =================
  int aO[4];
#pragma unroll
  for (int m = 0; m < 4; ++m) aO[m] = swz((wr * 64 + m * 16 + fr) * 128 + fg * 16);
  int bO[4];
#pragma unroll
  for (int j = 0; j < 4; ++j) bO[j] = swz((wc * 128 + j * 16 + fr) * 64 + fg * 16);

  const u16* bSrcP[4];
#pragma unroll
  for (int i = 0; i < 4; ++i) {
    int P = (w * 4 + i) * 1024 + lane * 16;
    int U = swz(P);
    bSrcP[i] = Wb + (size_t)(U >> 6) * KP0 + ((U & 63) >> 1);
  }
  const float* xRow[2]; int aKc[2];
#pragma unroll
  for (int c2 = 0; c2 < 2; ++c2) {
    int P = c2 * 8192 + t * 16;
    int U = swz(P);
    xRow[c2] = x + (rbase + (U >> 7)) * (size_t)784;
    aKc[c2] = (U & 127) >> 1;
  }

  f32x4 acc[4][8];
#pragma unroll
  for (int m = 0; m < 4; ++m)
#pragma unroll
    for (int n = 0; n < 8; ++n) acc[m][n] = (f32x4){0.f, 0.f, 0.f, 0.f};

  bhalf8 afA[4], bf[4];
  f32x4 xrE[2][2], xrO[2][2];

  auto loadX = [&](int tt2, f32x4 (&xr)[2][2]) {
#pragma unroll
    for (int c2 = 0; c2 < 2; ++c2) {
      int k = tt2 * 64 + aKc[c2];
      const float* p = xRow[c2] + ((k < 784) ? k : 0);
      xr[c2][0] = *(const f32x4*)p; xr[c2][1] = *(const f32x4*)(p + 4);
    }
  };
  auto cvtW = [&](int aB, f32x4 (&xr)[2][2]) {
#pragma unroll
    for (int c2 = 0; c2 < 2; ++c2) {
      u16x8 v;
#pragma unroll
      for (int j = 0; j < 4; ++j) { v[j] = f2bf(xr[c2][0][j]); v[4 + j] = f2bf(xr[c2][1][j]); }
      *(u16x8*)(lds + aB + c2 * 8192 + t * 16) = v;
    }
  };
  auto gllLo = [&](int H) {
    char* bb = lds + 32768 + (H % 3) * 32768;
    GLL16(bSrcP[0] + H * 32, bb + (w * 4 + 0) * 1024);
    GLL16(bSrcP[1] + H * 32, bb + (w * 4 + 1) * 1024);
  };
  auto gllHi = [&](int H) {
    char* bb = lds + 32768 + (H % 3) * 32768;
    GLL16(bSrcP[2] + H * 32, bb + (w * 4 + 2) * 1024);
    GLL16(bSrcP[3] + H * 32, bb + (w * 4 + 3) * 1024);
  };
  auto rdA = [&](int aB, int ks) {
#pragma unroll
    for (int m = 0; m < 4; ++m)
      afA[m] = *(const bhalf8*)(lds + aB + (aO[m] ^ (ks << 6)));
  };
  auto rdBq = [&](int H, int hi) {
    const char* bb = lds + 32768 + (H % 3) * 32768 + hi * 4096;
#pragma unroll
    for (int j = 0; j < 4; ++j) bf[j] = *(const bhalf8*)(bb + bO[j]);
  };
  auto mfmaLoQ = [&]() {
    __builtin_amdgcn_s_setprio(1);
#pragma unroll
    for (int m = 0; m < 4; ++m)
#pragma unroll
      for (int n = 0; n < 4; ++n)
        acc[m][n] = __builtin_amdgcn_mfma_f32_16x16x32_bf16(afA[m], bf[n], acc[m][n], 0, 0, 0);
    __builtin_amdgcn_s_setprio(0);
  };
  auto mfmaHiQ = [&]() {
    __builtin_amdgcn_s_setprio(1);
#pragma unroll
    for (int m = 0; m < 4; ++m)
#pragma unroll
      for (int n = 0; n < 4; ++n)
        acc[m][4 + n] = __builtin_amdgcn_mfma_f32_16x16x32_bf16(afA[m], bf[n], acc[m][4 + n], 0, 0, 0);
    __builtin_amdgcn_s_setprio(0);
  };

  auto tile = [&](int tt, f32x4 (&xrLd)[2][2], f32x4 (&xrCv)[2][2],
                  bool doStage, bool doX, int vmPh4, bool vm0Ph2) {
    const int aB = (tt & 1) * 16384;
    const int H0 = 2 * tt, H1 = 2 * tt + 1;
    rdA(aB, 0); rdBq(H0, 0);
    if (doStage) gllLo(H0 + 2);
    __builtin_amdgcn_s_barrier();
    asm volatile("s_waitcnt lgkmcnt(0)" ::: "memory"); SB();
    mfmaLoQ();
    __builtin_amdgcn_s_barrier();
    rdBq(H0, 1);
    if (doStage) gllHi(H0 + 2);
    __builtin_amdgcn_s_barrier();
    asm volatile("s_waitcnt lgkmcnt(0)" ::: "memory"); SB();
    mfmaHiQ();
    if (vm0Ph2) { asm volatile("s_waitcnt vmcnt(0)" ::: "memory"); }
    else        { asm volatile("s_waitcnt vmcnt(4)" ::: "memory"); }
    __builtin_amdgcn_s_barrier();
    rdA(aB, 1); rdBq(H1, 0);
    if (doStage) gllLo(H1 + 2);
    if (doX) loadX(tt + 2, xrLd);
    __builtin_amdgcn_s_barrier();
    asm volatile("s_waitcnt lgkmcnt(0)" ::: "memory"); SB();
    mfmaLoQ();
    __builtin_amdgcn_s_barrier();
    rdBq(H1, 1);
    if (tt < 12) cvtW(aB ^ 16384, xrCv);
    if (doStage) gllHi(H1 + 2);
    __builtin_amdgcn_s_barrier();
    asm volatile("s_waitcnt lgkmcnt(0)" ::: "memory"); SB();
    mfmaHiQ();
    if (vmPh4 == 8)      { asm volatile("s_waitcnt vmcnt(8)" ::: "memory"); }
    else if (vmPh4 == 4) { asm volatile("s_waitcnt vmcnt(4)" ::: "memory"); }
    __builtin_amdgcn_s_barrier();
  };

  gllLo(0); gllHi(0);
  gllLo(1); gllHi(1);
  loadX(0, xrE);
  loadX(1, xrO);
  cvtW(0, xrE);
  asm volatile("s_waitcnt lgkmcnt(0)" ::: "memory");
  __builtin_amdgcn_s_barrier();

  for (int i = 0; i < 5; ++i) {
    tile(2 * i,     xrE, xrO, true, true, 8, false);
    tile(2 * i + 1, xrO, xrE, true, true, 8, false);
  }
  tile(10, xrE, xrO, true,  true,  8, false);
  tile(11, xrO, xrE, true,  false, 4, false);
  tile(12, xrE, xrO, false, false, -1, true);
  // acc[4][8] now holds the block's full 128x512 m1 tile (pre-relu). No global write.

  // ================= layers 2+3, per 64-row half =================
  const int wr2 = w >> 2, wc2 = w & 3;   // layer-2 wave map: 2M x 4N on [64][256]
  // W1 staging sources, pre-swizzled for [256 rows][64 elems] (128B-row) tiles
  const u16* w1Src[4];
#pragma unroll
  for (int i = 0; i < 4; ++i) {
    int P = (w * 4 + i) * 1024 + lane * 16;
    int U = swz(P);
    w1Src[i] = W1b + (size_t)(U >> 7) * 512 + ((U & 127) >> 1);
  }
  // layer-2 A-frag byte offsets into m1-half [64][512] (1024B rows, swz2); +128/ tile kt
  int a2O[2];
#pragma unroll
  for (int m = 0; m < 2; ++m) a2O[m] = (wr2 * 32 + m * 16 + fr) * 1024 + fg * 16;
  int b2O[4];
#pragma unroll
  for (int n = 0; n < 4; ++n) b2O[n] = (wc2 * 64 + n * 16 + fr) * 128 + fg * 16;

  for (int h = 0; h < 2; ++h) {
    // ---- scatter relu(m1 half) -> LDS [64][512] bf16, swz2 ----
    if (wr == h) {
#pragma unroll
      for (int m = 0; m < 4; ++m)
#pragma unroll
        for (int n = 0; n < 8; ++n)
#pragma unroll
          for (int q = 0; q < 4; ++q) {
            int row = m * 16 + fg * 4 + q;            // 0..63 within half
            int col = wc * 128 + n * 16 + fr;         // 0..511
            float vv = acc[m][n][q];
            vv = vv > 0.f ? vv : 0.f;
            *(u16*)(lds + swz2(row * 1024 + col * 2)) = f2bf(vv);
          }
    }
    __syncthreads();

    // ---- layer 2: m2[64][256] = relu(m1h @ W1^T), K=512, BK=64, dbuf W1 tiles ----
    f32x4 acc2[2][4];
#pragma unroll
    for (int m = 0; m < 2; ++m)
#pragma unroll
      for (int n = 0; n < 4; ++n) acc2[m][n] = (f32x4){0.f, 0.f, 0.f, 0.f};

#pragma unroll
    for (int i = 0; i < 4; ++i) GLL16(w1Src[i], lds + 65536 + (w * 4 + i) * 1024);

    for (int kt = 0; kt < 8; ++kt) {
      const char* wb = lds + 65536 + (kt & 1) * 32768;
      asm volatile("s_waitcnt vmcnt(0)" ::: "memory");
      __syncthreads();
      if (kt < 7) {
#pragma unroll
        for (int i = 0; i < 4; ++i)
          GLL16(w1Src[i] + (kt + 1) * 64, lds + 65536 + ((kt + 1) & 1) * 32768 + (w * 4 + i) * 1024);
      }
#pragma unroll
      for (int ks = 0; ks < 2; ++ks) {
        bhalf8 a2[2], b2[4];
#pragma unroll
        for (int m = 0; m < 2; ++m)
          a2[m] = *(const bhalf8*)(lds + swz2(a2O[m] + kt * 128 + ks * 64));
#pragma unroll
        for (int n = 0; n < 4; ++n)
          b2[n] = *(const bhalf8*)(wb + swz(b2O[n] + ks * 64));
        __builtin_amdgcn_s_setprio(1);
#pragma unroll
        for (int m = 0; m < 2; ++m)
#pragma unroll
          for (int n = 0; n < 4; ++n)
            acc2[m][n] = __builtin_amdgcn_mfma_f32_16x16x32_bf16(a2[m], b2[n], acc2[m][n], 0, 0, 0);
        __builtin_amdgcn_s_setprio(0);
      }
    }
    __syncthreads();   // all reads of m1h / W1 bufs done

    // ---- m2 -> LDS [64][264] @65536; W2 [16][264] @99328 ----
    u16* m2s = (u16*)(lds + 65536);
    u16* W2s = (u16*)(lds + 99328);
    {
      int r = t >> 5, kc = (t & 31) * 8;
      *(int4*)&W2s[r * 264 + kc] = *(const int4*)(W2b + r * 256 + kc);
    }
#pragma unroll
    for (int m = 0; m < 2; ++m)
#pragma unroll
      for (int n = 0; n < 4; ++n)
#pragma unroll
        for (int q = 0; q < 4; ++q) {
          int row = wr2 * 32 + m * 16 + fg * 4 + q;
          int col = wc2 * 64 + n * 16 + fr;
          float vv = acc2[m][n][q];
          vv = vv > 0.f ? vv : 0.f;
          m2s[row * 264 + col] = f2bf(vv);
        }
    __syncthreads();

    // ---- layer 3: waves 0-3, 16 rows each; K=256 ----
    if (w < 4) {
      f32x4 acc3 = (f32x4){0.f, 0.f, 0.f, 0.f};
      const int arow = w * 16 + fr;
#pragma unroll
      for (int ks = 0; ks < 8; ++ks) {
        bhalf8 a = *(const bhalf8*)&m2s[arow * 264 + ks * 32 + fg * 8];
        bhalf8 b = *(const bhalf8*)&W2s[fr * 264 + ks * 32 + fg * 8];
        acc3 = __builtin_amdgcn_mfma_f32_16x16x32_bf16(a, b, acc3, 0, 0, 0);
      }
      if (fr < 10) {
#pragma unroll
        for (int q = 0; q < 4; ++q) {
          size_t row = rbase + h * 64 + w * 16 + fg * 4 + q;
          float vv = acc3[q];
          out[row * 10 + fr] = vv > 0.f ? vv : 0.f;
        }
      }
    }
    __syncthreads();   // LDS fully reusable for next half
  }
}

extern "C" void kernel_launch(void* const* d_in, const int* in_sizes, int n_in,
                              void* d_out, int out_size, void* d_ws, size_t ws_size,
                              hipStream_t stream) {
  const float* x  = (const float*)d_in[0];
  const float* W0 = (const float*)d_in[1];
  const float* W1 = (const float*)d_in[2];
  const float* W2 = (const float*)d_in[3];
  float* out = (float*)d_out;

  char* ws = (char*)d_ws;
  u16* W0b = (u16*)(ws);                    // 512x832 = 851968 B
  u16* W1b = (u16*)(ws + 851968);           // 256x512 = 262144 B
  u16* W2b = (u16*)(ws + 1114112);          // 16x256  = 8192 B

  hipFuncSetAttribute((const void*)fused3,
                      hipFuncAttributeMaxDynamicSharedMemorySize, 131072);

  cvt_weights<<<dim3((W0E + W1E + W2E + 255) / 256), dim3(256), 0, stream>>>(
      W0, W1, W2, W0b, W1b, W2b);

  // all three layers fused; m1/m2 never touch HBM
  fused3<<<dim3(256), dim3(512), 131072, stream>>>(x, W0b, W1b, W2b, out);
}

// Round 14
// 53.830 us; speedup vs baseline: 2.6019x; 2.6019x over previous
//
#include <hip/hip_runtime.h>

typedef __bf16 bhalf;
typedef bhalf bhalf8 __attribute__((ext_vector_type(8)));
typedef float f32x4 __attribute__((ext_vector_type(4)));
typedef unsigned short u16;
typedef u16 u16x8 __attribute__((ext_vector_type(8)));

__device__ __forceinline__ u16 f2bf(float f) {
  union { float f; unsigned u; } v; v.f = f;
  unsigned r = v.u + 0x7FFFu + ((v.u >> 16) & 1u);
  return (u16)(r >> 16);
}

// Involutions flipping byte bits 4-6:
// swz  : key bits 7-9   (64B/128B-row staging tiles; proven r5-r12, 0 conflicts)
// swzM : key (row ^ row>>3)&7 for 1024B-row m1 tile — conflict-free for BOTH the
//        column-order scatter writes (keys distinct across fg,q) and the row-order
//        layer-2 reads (16 rows -> 8 keys x 2-way = free).
__device__ __forceinline__ int swz(int L)  { return L ^ (((L >> 7) & 7) << 4); }
__device__ __forceinline__ int swzM(int L) { return L ^ ((((L >> 10) ^ (L >> 13)) & 7) << 4); }

#define GLL16(gp, lp) __builtin_amdgcn_global_load_lds( \
    (const __attribute__((address_space(1))) unsigned int*)(gp), \
    (__attribute__((address_space(3))) unsigned int*)(lp), 16, 0, 0)

#define SB() __builtin_amdgcn_sched_barrier(0)

// W0: [512][784] f32 -> bf16 [512][832] zero-pad (13 K-tiles of 64); W1: [256][512]; W2 pad 16x256.
#define KP0 832
#define W0E (512 * KP0)
#define W1E (256 * 512)
#define W2E (16 * 256)

__global__ __launch_bounds__(256) void cvt_weights(
    const float* __restrict__ W0, const float* __restrict__ W1,
    const float* __restrict__ W2,
    u16* __restrict__ W0b, u16* __restrict__ W1b, u16* __restrict__ W2b)
{
  int i = blockIdx.x * 256 + threadIdx.x;
  if (i < W0E) {
    int r = i / KP0, k = i - r * KP0;
    W0b[i] = (k < 784) ? f2bf(W0[r * 784 + k]) : (u16)0;
    return;
  }
  i -= W0E;
  if (i < W1E) { W1b[i] = f2bf(W1[i]); return; }
  i -= W1E;
  if (i < W2E) {
    int r = i >> 8, c = i & 255;
    W2b[i] = (r < 10) ? f2bf(W2[r * 256 + c]) : (u16)0;
  }
}

// FUSED 3 layers, spill-free. Block = 128 rows, 8 waves. Layer-1: r12's 8-phase
// 128x512 (x read once). Then IMMEDIATE full scatter relu(m1)->LDS[128][512] (swzM;
// acc dies here -> no spill). Layer-2: K=512 BK=32 dbuf W1 (gll). m2/W2 reuse dead
// m1 LDS; layer-3: 8 waves x 16 rows -> out. LDS = 160 KB (1 block/CU, as r12).
__global__ __launch_bounds__(512) void fused3(
    const float* __restrict__ x, const u16* __restrict__ Wb,
    const u16* __restrict__ W1b, const u16* __restrict__ W2b,
    float* __restrict__ out)
{
  extern __shared__ u16 ldsu[];      // 160 KB dynamic
  char* lds = (char*)ldsu;
  const int t = threadIdx.x, w = t >> 6, lane = t & 63;
  const size_t rbase = (size_t)blockIdx.x * 128;
  const int wr = w >> 2, wc = w & 3, fr = lane & 15, fg = lane >> 4;

  // ================= layer 1 (r12 8-phase, verbatim) =================
  int aO[4];
#pragma unroll
  for (int m = 0; m < 4; ++m) aO[m] = swz((wr * 64 + m * 16 + fr) * 128 + fg * 16);
  int bO[4];
#pragma unroll
  for (int j = 0; j < 4; ++j) bO[j] = swz((wc * 128 + j * 16 + fr) * 64 + fg * 16);

  const u16* bSrcP[4];
#pragma unroll
  for (int i = 0; i < 4; ++i) {
    int P = (w * 4 + i) * 1024 + lane * 16;
    int U = swz(P);
    bSrcP[i] = Wb + (size_t)(U >> 6) * KP0 + ((U & 63) >> 1);
  }
  const float* xRow[2]; int aKc[2];
#pragma unroll
  for (int c2 = 0; c2 < 2; ++c2) {
    int P = c2 * 8192 + t * 16;
    int U = swz(P);
    xRow[c2] = x + (rbase + (U >> 7)) * (size_t)784;
    aKc[c2] = (U & 127) >> 1;
  }

  f32x4 acc[4][8];
#pragma unroll
  for (int m = 0; m < 4; ++m)
#pragma unroll
    for (int n = 0; n < 8; ++n) acc[m][n] = (f32x4){0.f, 0.f, 0.f, 0.f};

  bhalf8 afA[4], bf[4];
  f32x4 xrE[2][2], xrO[2][2];

  auto loadX = [&](int tt2, f32x4 (&xr)[2][2]) {
#pragma unroll
    for (int c2 = 0; c2 < 2; ++c2) {
      int k = tt2 * 64 + aKc[c2];
      const float* p = xRow[c2] + ((k < 784) ? k : 0);
      xr[c2][0] = *(const f32x4*)p; xr[c2][1] = *(const f32x4*)(p + 4);
    }
  };
  auto cvtW = [&](int aB, f32x4 (&xr)[2][2]) {
#pragma unroll
    for (int c2 = 0; c2 < 2; ++c2) {
      u16x8 v;
#pragma unroll
      for (int j = 0; j < 4; ++j) { v[j] = f2bf(xr[c2][0][j]); v[4 + j] = f2bf(xr[c2][1][j]); }
      *(u16x8*)(lds + aB + c2 * 8192 + t * 16) = v;
    }
  };
  auto gllLo = [&](int H) {
    char* bb = lds + 32768 + (H % 3) * 32768;
    GLL16(bSrcP[0] + H * 32, bb + (w * 4 + 0) * 1024);
    GLL16(bSrcP[1] + H * 32, bb + (w * 4 + 1) * 1024);
  };
  auto gllHi = [&](int H) {
    char* bb = lds + 32768 + (H % 3) * 32768;
    GLL16(bSrcP[2] + H * 32, bb + (w * 4 + 2) * 1024);
    GLL16(bSrcP[3] + H * 32, bb + (w * 4 + 3) * 1024);
  };
  auto rdA = [&](int aB, int ks) {
#pragma unroll
    for (int m = 0; m < 4; ++m)
      afA[m] = *(const bhalf8*)(lds + aB + (aO[m] ^ (ks << 6)));
  };
  auto rdBq = [&](int H, int hi) {
    const char* bb = lds + 32768 + (H % 3) * 32768 + hi * 4096;
#pragma unroll
    for (int j = 0; j < 4; ++j) bf[j] = *(const bhalf8*)(bb + bO[j]);
  };
  auto mfmaLoQ = [&]() {
    __builtin_amdgcn_s_setprio(1);
#pragma unroll
    for (int m = 0; m < 4; ++m)
#pragma unroll
      for (int n = 0; n < 4; ++n)
        acc[m][n] = __builtin_amdgcn_mfma_f32_16x16x32_bf16(afA[m], bf[n], acc[m][n], 0, 0, 0);
    __builtin_amdgcn_s_setprio(0);
  };
  auto mfmaHiQ = [&]() {
    __builtin_amdgcn_s_setprio(1);
#pragma unroll
    for (int m = 0; m < 4; ++m)
#pragma unroll
      for (int n = 0; n < 4; ++n)
        acc[m][4 + n] = __builtin_amdgcn_mfma_f32_16x16x32_bf16(afA[m], bf[n], acc[m][4 + n], 0, 0, 0);
    __builtin_amdgcn_s_setprio(0);
  };

  auto tile = [&](int tt, f32x4 (&xrLd)[2][2], f32x4 (&xrCv)[2][2],
                  bool doStage, bool doX, int vmPh4, bool vm0Ph2) {
    const int aB = (tt & 1) * 16384;
    const int H0 = 2 * tt, H1 = 2 * tt + 1;
    rdA(aB, 0); rdBq(H0, 0);
    if (doStage) gllLo(H0 + 2);
    __builtin_amdgcn_s_barrier();
    asm volatile("s_waitcnt lgkmcnt(0)" ::: "memory"); SB();
    mfmaLoQ();
    __builtin_amdgcn_s_barrier();
    rdBq(H0, 1);
    if (doStage) gllHi(H0 + 2);
    __builtin_amdgcn_s_barrier();
    asm volatile("s_waitcnt lgkmcnt(0)" ::: "memory"); SB();
    mfmaHiQ();
    if (vm0Ph2) { asm volatile("s_waitcnt vmcnt(0)" ::: "memory"); }
    else        { asm volatile("s_waitcnt vmcnt(4)" ::: "memory"); }
    __builtin_amdgcn_s_barrier();
    rdA(aB, 1); rdBq(H1, 0);
    if (doStage) gllLo(H1 + 2);
    if (doX) loadX(tt + 2, xrLd);
    __builtin_amdgcn_s_barrier();
    asm volatile("s_waitcnt lgkmcnt(0)" ::: "memory"); SB();
    mfmaLoQ();
    __builtin_amdgcn_s_barrier();
    rdBq(H1, 1);
    if (tt < 12) cvtW(aB ^ 16384, xrCv);
    if (doStage) gllHi(H1 + 2);
    __builtin_amdgcn_s_barrier();
    asm volatile("s_waitcnt lgkmcnt(0)" ::: "memory"); SB();
    mfmaHiQ();
    if (vmPh4 == 8)      { asm volatile("s_waitcnt vmcnt(8)" ::: "memory"); }
    else if (vmPh4 == 4) { asm volatile("s_waitcnt vmcnt(4)" ::: "memory"); }
    __builtin_amdgcn_s_barrier();
  };

  gllLo(0); gllHi(0);
  gllLo(1); gllHi(1);
  loadX(0, xrE);
  loadX(1, xrO);
  cvtW(0, xrE);
  asm volatile("s_waitcnt lgkmcnt(0)" ::: "memory");
  __builtin_amdgcn_s_barrier();

  for (int i = 0; i < 5; ++i) {
    tile(2 * i,     xrE, xrO, true, true, 8, false);
    tile(2 * i + 1, xrO, xrE, true, true, 8, false);
  }
  tile(10, xrE, xrO, true,  true,  8, false);
  tile(11, xrO, xrE, true,  false, 4, false);
  tile(12, xrE, xrO, false, false, -1, true);
  // all staging drained; acc holds the 128x512 m1 tile (pre-relu)

  // ====== layer-2 W1 staging sources (pre-swizzled, [256][32] 64B-row tiles) ======
  const u16* w1Src[2];
#pragma unroll
  for (int i = 0; i < 2; ++i) {
    int P = (w * 2 + i) * 1024 + lane * 16;
    int U = swz(P);
    w1Src[i] = W1b + (size_t)(U >> 6) * 512 + ((U & 63) >> 1);
  }
  // issue W1 tile-0 glls now: they fly under the m1 scatter
#pragma unroll
  for (int i = 0; i < 2; ++i) GLL16(w1Src[i], lds + 131072 + (w * 2 + i) * 1024);

  // ====== scatter relu(m1) -> LDS [128][512] bf16 (1024B rows, swzM); acc DIES ======
#pragma unroll
  for (int m = 0; m < 4; ++m)
#pragma unroll
    for (int n = 0; n < 8; ++n)
#pragma unroll
      for (int q = 0; q < 4; ++q) {
        int row = wr * 64 + m * 16 + fg * 4 + q;
        int col = wc * 128 + n * 16 + fr;
        float vv = acc[m][n][q];
        vv = vv > 0.f ? vv : 0.f;
        *(u16*)(lds + swzM(row * 1024 + col * 2)) = f2bf(vv);
      }
  __syncthreads();

  // ====== layer 2: m2[128][256] = relu(m1 @ W1^T), K=512, BK=32, 16 dbuf steps ======
  int a2O[4], b2O[4];
#pragma unroll
  for (int m = 0; m < 4; ++m) a2O[m] = (wr * 64 + m * 16 + fr) * 1024 + fg * 16;
#pragma unroll
  for (int n = 0; n < 4; ++n) b2O[n] = (wc * 64 + n * 16 + fr) * 64 + fg * 16;

  f32x4 acc2[4][4];
#pragma unroll
  for (int m = 0; m < 4; ++m)
#pragma unroll
    for (int n = 0; n < 4; ++n) acc2[m][n] = (f32x4){0.f, 0.f, 0.f, 0.f};

  for (int kt = 0; kt < 16; ++kt) {
    const char* wbuf = lds + 131072 + (kt & 1) * 16384;
    asm volatile("s_waitcnt vmcnt(0)" ::: "memory");
    __syncthreads();
    if (kt < 15) {
#pragma unroll
      for (int i = 0; i < 2; ++i)
        GLL16(w1Src[i] + (kt + 1) * 32,
              lds + 131072 + ((kt + 1) & 1) * 16384 + (w * 2 + i) * 1024);
    }
    bhalf8 a2[4], b2[4];
#pragma unroll
    for (int m = 0; m < 4; ++m)
      a2[m] = *(const bhalf8*)(lds + swzM(a2O[m] + kt * 64));
#pragma unroll
    for (int n = 0; n < 4; ++n)
      b2[n] = *(const bhalf8*)(wbuf + swz(b2O[n]));
    __builtin_amdgcn_s_setprio(1);
#pragma unroll
    for (int m = 0; m < 4; ++m)
#pragma unroll
      for (int n = 0; n < 4; ++n)
        acc2[m][n] = __builtin_amdgcn_mfma_f32_16x16x32_bf16(a2[m], b2[n], acc2[m][n], 0, 0, 0);
    __builtin_amdgcn_s_setprio(0);
  }
  __syncthreads();   // all m1 / W1-buf reads done; m1 region reusable

  // ====== m2 -> LDS [128][264] @0; W2 [16][264] @67584; layer 3 -> out ======
  u16* m2s = (u16*)lds;
  u16* W2s = (u16*)(lds + 67584);
  {
    int r = t >> 5, kc = (t & 31) * 8;
    *(int4*)&W2s[r * 264 + kc] = *(const int4*)(W2b + r * 256 + kc);
  }
#pragma unroll
  for (int m = 0; m < 4; ++m)
#pragma unroll
    for (int n = 0; n < 4; ++n)
#pragma unroll
      for (int q = 0; q < 4; ++q) {
        int row = wr * 64 + m * 16 + fg * 4 + q;
        int col = wc * 64 + n * 16 + fr;
        float vv = acc2[m][n][q];
        vv = vv > 0.f ? vv : 0.f;
        m2s[row * 264 + col] = f2bf(vv);
      }
  __syncthreads();

  // layer 3: 8 waves x 16 rows, K=256
  {
    f32x4 acc3 = (f32x4){0.f, 0.f, 0.f, 0.f};
    const int arow = w * 16 + fr;
#pragma unroll
    for (int ks = 0; ks < 8; ++ks) {
      bhalf8 a = *(const bhalf8*)&m2s[arow * 264 + ks * 32 + fg * 8];
      bhalf8 b = *(const bhalf8*)&W2s[fr * 264 + ks * 32 + fg * 8];
      acc3 = __builtin_amdgcn_mfma_f32_16x16x32_bf16(a, b, acc3, 0, 0, 0);
    }
    if (fr < 10) {
#pragma unroll
      for (int q = 0; q < 4; ++q) {
        size_t row = rbase + w * 16 + fg * 4 + q;
        float vv = acc3[q];
        out[row * 10 + fr] = vv > 0.f ? vv : 0.f;
      }
    }
  }
}

extern "C" void kernel_launch(void* const* d_in, const int* in_sizes, int n_in,
                              void* d_out, int out_size, void* d_ws, size_t ws_size,
                              hipStream_t stream) {
  const float* x  = (const float*)d_in[0];
  const float* W0 = (const float*)d_in[1];
  const float* W1 = (const float*)d_in[2];
  const float* W2 = (const float*)d_in[3];
  float* out = (float*)d_out;

  char* ws = (char*)d_ws;
  u16* W0b = (u16*)(ws);                    // 512x832 = 851968 B
  u16* W1b = (u16*)(ws + 851968);           // 256x512 = 262144 B
  u16* W2b = (u16*)(ws + 1114112);          // 16x256  = 8192 B

  hipFuncSetAttribute((const void*)fused3,
                      hipFuncAttributeMaxDynamicSharedMemorySize, 163840);

  cvt_weights<<<dim3((W0E + W1E + W2E + 255) / 256), dim3(256), 0, stream>>>(
      W0, W1, W2, W0b, W1b, W2b);

  // all three layers fused; m1/m2 never touch HBM; no register state crosses layers
  fused3<<<dim3(256), dim3(512), 163840, stream>>>(x, W0b, W1b, W2b, out);
}